// Round 4
// baseline (1707.308 us; speedup 1.0000x reference)
//
#include <hip/hip_runtime.h>
#include <hip/hip_bf16.h>
#include <math.h>

#define H_DIM 2048
#define N_ST 8
#define B_SZ 4
#define L_SEQ 4096
#define DMODEL 1024
#define DCONV 4
#define CL 128
#define NC (L_SEQ / CL)   // 32

typedef __bf16 bf16x8 __attribute__((ext_vector_type(8)));
typedef __bf16 bf16x4 __attribute__((ext_vector_type(4)));
typedef float f32x4 __attribute__((ext_vector_type(4)));

typedef const unsigned int __attribute__((address_space(1)))* gptr_t;
typedef unsigned int __attribute__((address_space(3)))* lptr_t;

__device__ __forceinline__ void gl_lds16(const __bf16* g, __bf16* l) {
    __builtin_amdgcn_global_load_lds((gptr_t)g, (lptr_t)l, 16, 0, 0);
}

// -------- workspace layout (floats), total ~28.7M f = 114.7 MB --------
#define WS_XZ     0
#define WS_YTH    8388608
#define WS_YTL    12582912
#define WS_COEF   16777216
#define WS_STATES 16875520
#define WS_LOOK   17924096
#define WS_HH     18186240
#define WS_HL     20283392
#define WS_WIH    22380544
#define WS_WIL    24477696
#define WS_WOH    26574848
#define WS_WOL    27623424

// ============ split f32 -> bf16 hi/lo planes ============
__global__ __launch_bounds__(256) void cvt_split4(const float* __restrict__ s,
                                                  __bf16* __restrict__ h,
                                                  __bf16* __restrict__ l, int n4) {
    int i = blockIdx.x * 256 + threadIdx.x;
    if (i >= n4) return;
    float4 v = ((const float4*)s)[i];
    float vv[4] = {v.x, v.y, v.z, v.w};
    bf16x4 hv, lv;
#pragma unroll
    for (int j = 0; j < 4; ++j) {
        __bf16 hb = (__bf16)vv[j];
        hv[j] = hb;
        lv[j] = (__bf16)(vv[j] - (float)hb);
    }
    *(bf16x4*)&h[(size_t)i * 4] = hv;
    *(bf16x4*)&l[(size_t)i * 4] = lv;
}

// ============ coefficient precompute ============
__global__ void coef_kernel(const float* __restrict__ log_dt,
                            const float* __restrict__ log_A_real,
                            const float* __restrict__ A_imag,
                            const float* __restrict__ C_re,
                            const float* __restrict__ C_im,
                            float* __restrict__ coef) {
    int i = blockIdx.x * blockDim.x + threadIdx.x;
    if (i >= H_DIM * N_ST) return;
    int h = i >> 3;
    float dt = expf(log_dt[h]);
    float Ar = -expf(log_A_real[i]);
    float Ai = A_imag[i];
    float er = expf(dt * Ar);
    float ang = dt * Ai;
    float wr = er * cosf(ang);
    float wi = er * sinf(ang);
    float den = Ar * Ar + Ai * Ai;
    float qr = ((wr - 1.f) * Ar + wi * Ai) / den;
    float qi = (wi * Ar - (wr - 1.f) * Ai) / den;
    float Cr = C_re[i], Ci = C_im[i];
    float Ctr = Cr * qr - Ci * qi;
    float Cti = Cr * qi + Ci * qr;
    float eCL = expf((float)CL * dt * Ar);
    float aCL = (float)CL * dt * Ai;
    float pr = eCL * cosf(aCL);
    float pi = eCL * sinf(aCL);
    const int HN = H_DIM * N_ST;
    coef[i]          = wr;
    coef[HN + i]     = wi;
    coef[2 * HN + i] = Ctr;
    coef[3 * HN + i] = Cti;
    coef[4 * HN + i] = pr;
    coef[5 * HN + i] = pi;
}

// ============ split-bf16 MFMA GEMM (B^T form), double-buffered + counted vmcnt ============
// C[M][N] = sum_k A[m][k]*B[n][k]; C = Ah*Bh + Ah*Bl + Al*Bh (fp32 accum).
// 128x128 tile, 4 waves (2x2), BK=32, LDS dbuf. 1-D grid with XCD swizzle.
__global__ __launch_bounds__(256, 2) void gemm_split(const __bf16* __restrict__ Ah,
                                                     const __bf16* __restrict__ Al,
                                                     const __bf16* __restrict__ Bh,
                                                     const __bf16* __restrict__ Bl,
                                                     float* __restrict__ C,
                                                     int K, int ldc, int gx) {
    __shared__ __bf16 sAh[2][4096], sAl[2][4096], sBh[2][4096], sBl[2][4096];
    const int tid = threadIdx.x;
    const int lane = tid & 63;
    const int wid = tid >> 6;
    const int wrw = wid >> 1, wcw = wid & 1;

    // XCD-aware swizzle (bijective: gridDim.x % 8 == 0)
    const int nwg = gridDim.x;
    const int bid = blockIdx.x;
    const int swz = (bid & 7) * (nwg >> 3) + (bid >> 3);
    const int bn = swz % gx, bm = swz / gx;

    const int r = tid & 127;          // staging row within tile
    const int kbq8 = (tid >> 7) * 8;  // staging kb-oct offset
    const size_t arow = (size_t)(bm * 128 + r) * K;
    const size_t brow = (size_t)(bn * 128 + r) * K;

    f32x4 acc[4][4];
#pragma unroll
    for (int m = 0; m < 4; ++m)
#pragma unroll
        for (int n = 0; n < 4; ++n) acc[m][n] = (f32x4){0.f, 0.f, 0.f, 0.f};

    const int kb = lane >> 4, rr = lane & 15;

    auto stage = [&](int b, int k0) {
#pragma unroll
        for (int q = 0; q < 2; ++q) {
            const int lo = q * 2048 + tid * 8;
            const size_t go = (size_t)k0 + q * 16 + kbq8;
            gl_lds16(Ah + arow + go, &sAh[b][lo]);
            gl_lds16(Al + arow + go, &sAl[b][lo]);
            gl_lds16(Bh + brow + go, &sBh[b][lo]);
            gl_lds16(Bl + brow + go, &sBl[b][lo]);
        }
    };

    const int nt = K >> 5;
    stage(0, 0);
    stage(1, 32);

    for (int t = 0; t < nt; ++t) {
        const int cur = t & 1;
        // wait for tile t only; keep tile t+1's 8 loads/thread in flight
        if (t < nt - 1) asm volatile("s_waitcnt vmcnt(8)" ::: "memory");
        else            asm volatile("s_waitcnt vmcnt(0)" ::: "memory");
        __builtin_amdgcn_s_barrier();

        bf16x8 fAh[4], fAl[4], fBh[4], fBl[4];
#pragma unroll
        for (int m = 0; m < 4; ++m) {
            int off = kb * 1024 + (wrw * 64 + m * 16 + rr) * 8;
            fAh[m] = *(const bf16x8*)&sAh[cur][off];
            fAl[m] = *(const bf16x8*)&sAl[cur][off];
        }
#pragma unroll
        for (int n = 0; n < 4; ++n) {
            int off = kb * 1024 + (wcw * 64 + n * 16 + rr) * 8;
            fBh[n] = *(const bf16x8*)&sBh[cur][off];
            fBl[n] = *(const bf16x8*)&sBl[cur][off];
        }
#pragma unroll
        for (int m = 0; m < 4; ++m)
#pragma unroll
            for (int n = 0; n < 4; ++n) {
                acc[m][n] = __builtin_amdgcn_mfma_f32_16x16x32_bf16(fAh[m], fBh[n], acc[m][n], 0, 0, 0);
                acc[m][n] = __builtin_amdgcn_mfma_f32_16x16x32_bf16(fAh[m], fBl[n], acc[m][n], 0, 0, 0);
                acc[m][n] = __builtin_amdgcn_mfma_f32_16x16x32_bf16(fAl[m], fBh[n], acc[m][n], 0, 0, 0);
            }

        asm volatile("s_waitcnt lgkmcnt(0)" ::: "memory");
        __builtin_amdgcn_s_barrier();
        if (t + 2 < nt) stage(cur, (t + 2) << 5);
    }

    const int rq = lane >> 4;
#pragma unroll
    for (int m = 0; m < 4; ++m)
#pragma unroll
        for (int n = 0; n < 4; ++n) {
            int col = bn * 128 + wcw * 64 + n * 16 + rr;
            int row0 = bm * 128 + wrw * 64 + m * 16 + rq * 4;
#pragma unroll
            for (int j = 0; j < 4; ++j)
                C[(size_t)(row0 + j) * ldc + col] = acc[m][n][j];
        }
}

// ============ scan phase 1: local chunk scans (fused conv+SiLU) ============
__global__ __launch_bounds__(256) void scan_phase1(const float* __restrict__ xz,
                                                   const float* __restrict__ coef,
                                                   const float* __restrict__ conv_w,
                                                   const float* __restrict__ conv_b,
                                                   float* __restrict__ states,
                                                   float* __restrict__ look) {
    int t = blockIdx.x * 256 + threadIdx.x;   // t = h*NC + c
    int c = t & (NC - 1);
    int h = t >> 5;

    const int HN = H_DIM * N_ST;
    float wr[N_ST], wi[N_ST];
#pragma unroll
    for (int n = 0; n < N_ST; ++n) {
        wr[n] = coef[h * N_ST + n];
        wi[n] = coef[HN + h * N_ST + n];
    }
    float cw0 = conv_w[h * 4 + 0], cw1 = conv_w[h * 4 + 1];
    float cw2 = conv_w[h * 4 + 2], cw3 = conv_w[h * 4 + 3];
    float cb = conv_b[h];

    const float* xrow = xz + (size_t)h * L_SEQ + c * CL;
    float x3 = 0.f, x2 = 0.f, x1 = 0.f;
    if (c > 0) {
        float4 p = *(const float4*)(xrow - 4);
        x3 = p.y; x2 = p.z; x1 = p.w;
    }
    *(float4*)(look + (size_t)t * 4) = make_float4(x3, x2, x1, 0.f);

    float sr[N_ST], si[N_ST];
#pragma unroll
    for (int n = 0; n < N_ST; ++n) { sr[n] = 0.f; si[n] = 0.f; }

    for (int j = 0; j < CL; j += 4) {
        float4 v = *(const float4*)(xrow + j);
        float xv[4] = {v.x, v.y, v.z, v.w};
#pragma unroll
        for (int k = 0; k < 4; ++k) {
            float u = cw0 * x3 + cw1 * x2 + cw2 * x1 + cw3 * xv[k] + cb;
            float xc = u / (1.f + __expf(-u));
            x3 = x2; x2 = x1; x1 = xv[k];
#pragma unroll
            for (int n = 0; n < N_ST; ++n) {
                float nr = wr[n] * sr[n] - wi[n] * si[n] + xc;
                float ni = wr[n] * si[n] + wi[n] * sr[n];
                sr[n] = nr; si[n] = ni;
            }
        }
    }
    float* st = states + (size_t)t * (N_ST * 2);
#pragma unroll
    for (int n = 0; n < N_ST; ++n) { st[2 * n] = sr[n]; st[2 * n + 1] = si[n]; }
}

// ============ scan phase 2: combine chunk states -> chunk init states ============
__global__ __launch_bounds__(256) void scan_phase2(const float* __restrict__ coef,
                                                   float* __restrict__ states) {
    int h = blockIdx.x * 256 + threadIdx.x;
    if (h >= H_DIM) return;
    const int HN = H_DIM * N_ST;
    float pr[N_ST], pi[N_ST];
#pragma unroll
    for (int n = 0; n < N_ST; ++n) {
        pr[n] = coef[4 * HN + h * N_ST + n];
        pi[n] = coef[5 * HN + h * N_ST + n];
    }
    float sr[N_ST], si[N_ST];
#pragma unroll
    for (int n = 0; n < N_ST; ++n) { sr[n] = 0.f; si[n] = 0.f; }
    float* base = states + (size_t)h * NC * (N_ST * 2);
    for (int c = 0; c < NC; ++c) {
        float* st = base + c * (N_ST * 2);
#pragma unroll
        for (int n = 0; n < N_ST; ++n) {
            float lr = st[2 * n], li = st[2 * n + 1];
            st[2 * n] = sr[n]; st[2 * n + 1] = si[n];
            float nr = pr[n] * sr[n] - pi[n] * si[n] + lr;
            float ni = pr[n] * si[n] + pi[n] * sr[n] + li;
            sr[n] = nr; si[n] = ni;
        }
    }
}

// ============ scan phase 3: replay, fused D-skip + gate; writes y f32 OVER x ============
__global__ __launch_bounds__(256) void scan_phase3(float* __restrict__ xz,
                                                   const float* __restrict__ coef,
                                                   const float* __restrict__ conv_w,
                                                   const float* __restrict__ conv_b,
                                                   const float* __restrict__ Dvec,
                                                   const float* __restrict__ states,
                                                   const float* __restrict__ look) {
    int t = blockIdx.x * 256 + threadIdx.x;
    int c = t & (NC - 1);
    int h = t >> 5;

    const int HN = H_DIM * N_ST;
    float wr[N_ST], wi[N_ST], Ctr[N_ST], Cti[N_ST];
#pragma unroll
    for (int n = 0; n < N_ST; ++n) {
        wr[n]  = coef[h * N_ST + n];
        wi[n]  = coef[HN + h * N_ST + n];
        Ctr[n] = coef[2 * HN + h * N_ST + n];
        Cti[n] = coef[3 * HN + h * N_ST + n];
    }
    float cw0 = conv_w[h * 4 + 0], cw1 = conv_w[h * 4 + 1];
    float cw2 = conv_w[h * 4 + 2], cw3 = conv_w[h * 4 + 3];
    float cb = conv_b[h];
    float Dh = Dvec[h];

    float* xrow = xz + (size_t)h * L_SEQ + c * CL;
    const float* zrow = xz + (size_t)(H_DIM + h) * L_SEQ + c * CL;

    float4 lk = *(const float4*)(look + (size_t)t * 4);
    float x3 = lk.x, x2 = lk.y, x1 = lk.z;

    const float* st = states + (size_t)t * (N_ST * 2);
    float sr[N_ST], si[N_ST];
#pragma unroll
    for (int n = 0; n < N_ST; ++n) { sr[n] = st[2 * n]; si[n] = st[2 * n + 1]; }

    for (int j = 0; j < CL; j += 4) {
        float4 v = *(const float4*)(xrow + j);
        float4 zv = *(const float4*)(zrow + j);
        float xv[4] = {v.x, v.y, v.z, v.w};
        float zz[4] = {zv.x, zv.y, zv.z, zv.w};
        float out[4];
#pragma unroll
        for (int k = 0; k < 4; ++k) {
            float u = cw0 * x3 + cw1 * x2 + cw2 * x1 + cw3 * xv[k] + cb;
            float xc = u / (1.f + __expf(-u));
            x3 = x2; x2 = x1; x1 = xv[k];
            float accy = 0.f;
#pragma unroll
            for (int n = 0; n < N_ST; ++n) {
                float nr = wr[n] * sr[n] - wi[n] * si[n] + xc;
                float ni = wr[n] * si[n] + wi[n] * sr[n];
                sr[n] = nr; si[n] = ni;
                accy += Ctr[n] * nr - Cti[n] * ni;
            }
            float yv = 2.f * accy + Dh * xc;
            float g = zz[k] / (1.f + __expf(-zz[k]));
            out[k] = yv * g;
        }
        *(float4*)(xrow + j) = make_float4(out[0], out[1], out[2], out[3]);
    }
}

// ============ transpose + split: y f32 [H][L] -> yTh/yTl bf16 [L][H] ============
__global__ __launch_bounds__(256) void transpose_split(const float* __restrict__ y,
                                                       __bf16* __restrict__ th,
                                                       __bf16* __restrict__ tl) {
    __shared__ float tile[64][65];
    const int l0 = blockIdx.x * 64, h0 = blockIdx.y * 64;
    const int tid = threadIdx.x;
    const int r = tid >> 4, c4 = (tid & 15) * 4;
#pragma unroll
    for (int p = 0; p < 4; ++p) {
        float4 v = *(const float4*)(y + (size_t)(h0 + r + p * 16) * L_SEQ + l0 + c4);
        tile[r + p * 16][c4 + 0] = v.x;
        tile[r + p * 16][c4 + 1] = v.y;
        tile[r + p * 16][c4 + 2] = v.z;
        tile[r + p * 16][c4 + 3] = v.w;
    }
    __syncthreads();
    const int l = tid >> 2, hb = (tid & 3) * 16;
    float vals[16];
#pragma unroll
    for (int j = 0; j < 16; ++j) vals[j] = tile[hb + j][l];
    bf16x8 hv0, hv1, lv0, lv1;
#pragma unroll
    for (int j = 0; j < 8; ++j) {
        __bf16 hbv = (__bf16)vals[j];
        hv0[j] = hbv;
        lv0[j] = (__bf16)(vals[j] - (float)hbv);
        __bf16 hbv2 = (__bf16)vals[j + 8];
        hv1[j] = hbv2;
        lv1[j] = (__bf16)(vals[j + 8] - (float)hbv2);
    }
    size_t base = (size_t)(l0 + l) * H_DIM + h0 + hb;
    *(bf16x8*)&th[base] = hv0;
    *(bf16x8*)&th[base + 8] = hv1;
    *(bf16x8*)&tl[base] = lv0;
    *(bf16x8*)&tl[base + 8] = lv1;
}

extern "C" void kernel_launch(void* const* d_in, const int* in_sizes, int n_in,
                              void* d_out, int out_size, void* d_ws, size_t ws_size,
                              hipStream_t stream) {
    const float* hid        = (const float*)d_in[0];
    const float* W_in       = (const float*)d_in[1];
    const float* conv_w     = (const float*)d_in[2];
    const float* conv_b     = (const float*)d_in[3];
    const float* log_dt     = (const float*)d_in[4];
    const float* log_A_real = (const float*)d_in[5];
    const float* A_imag     = (const float*)d_in[6];
    const float* C_re       = (const float*)d_in[7];
    const float* C_im       = (const float*)d_in[8];
    const float* Dv         = (const float*)d_in[9];
    const float* W_out      = (const float*)d_in[10];
    float* out = (float*)d_out;
    float* ws  = (float*)d_ws;

    float* xz      = ws + WS_XZ;
    __bf16* yTh    = (__bf16*)(ws + WS_YTH);
    __bf16* yTl    = (__bf16*)(ws + WS_YTL);
    float* coef    = ws + WS_COEF;
    float* states  = ws + WS_STATES;
    float* look    = ws + WS_LOOK;
    __bf16* Hh     = (__bf16*)(ws + WS_HH);
    __bf16* Hl     = (__bf16*)(ws + WS_HL);
    __bf16* Wih    = (__bf16*)(ws + WS_WIH);
    __bf16* Wil    = (__bf16*)(ws + WS_WIL);
    __bf16* Woh    = (__bf16*)(ws + WS_WOH);
    __bf16* Wol    = (__bf16*)(ws + WS_WOL);

    coef_kernel<<<(H_DIM * N_ST + 255) / 256, 256, 0, stream>>>(
        log_dt, log_A_real, A_imag, C_re, C_im, coef);

    cvt_split4<<<(2 * H_DIM * DMODEL / 4 + 255) / 256, 256, 0, stream>>>(W_in, Wih, Wil, 2 * H_DIM * DMODEL / 4);
    cvt_split4<<<(DMODEL * H_DIM / 4 + 255) / 256, 256, 0, stream>>>(W_out, Woh, Wol, DMODEL * H_DIM / 4);

    const int nscan = H_DIM * NC;            // 65536
    const int nwgIn  = (L_SEQ / 128) * (2 * H_DIM / 128);  // 32*32 = 1024
    const int nwgOut = (DMODEL / 128) * (L_SEQ / 128);     // 8*32  = 256
    dim3 gTr(L_SEQ / 64, H_DIM / 64);        // (64,32)

    for (int b = 0; b < B_SZ; ++b) {
        const float* hid_b = hid + (size_t)b * L_SEQ * DMODEL;
        float* out_b = out + (size_t)b * L_SEQ * DMODEL;

        cvt_split4<<<(L_SEQ * DMODEL / 4 + 255) / 256, 256, 0, stream>>>(hid_b, Hh, Hl, L_SEQ * DMODEL / 4);
        gemm_split<<<nwgIn, 256, 0, stream>>>(Wih, Wil, Hh, Hl, xz, DMODEL, L_SEQ, L_SEQ / 128);
        scan_phase1<<<nscan / 256, 256, 0, stream>>>(xz, coef, conv_w, conv_b, states, look);
        scan_phase2<<<(H_DIM + 255) / 256, 256, 0, stream>>>(coef, states);
        scan_phase3<<<nscan / 256, 256, 0, stream>>>(xz, coef, conv_w, conv_b, Dv, states, look);
        transpose_split<<<gTr, 256, 0, stream>>>(xz, yTh, yTl);
        gemm_split<<<nwgOut, 256, 0, stream>>>(yTh, yTl, Woh, Wol, out_b, H_DIM, DMODEL, DMODEL / 128);
    }
}

// Round 5
// 1701.050 us; speedup vs baseline: 1.0037x; 1.0037x over previous
//
#include <hip/hip_runtime.h>
#include <hip/hip_bf16.h>
#include <math.h>

#define H_DIM 2048
#define N_ST 8
#define B_SZ 4
#define L_SEQ 4096
#define DMODEL 1024
#define DCONV 4
#define CL 128
#define NC (L_SEQ / CL)   // 32

typedef __bf16 bf16x8 __attribute__((ext_vector_type(8)));
typedef __bf16 bf16x4 __attribute__((ext_vector_type(4)));
typedef float f32x4 __attribute__((ext_vector_type(4)));

typedef const unsigned int __attribute__((address_space(1)))* gptr_t;
typedef unsigned int __attribute__((address_space(3)))* lptr_t;

__device__ __forceinline__ void gl_lds16(const __bf16* g, __bf16* l) {
    __builtin_amdgcn_global_load_lds((gptr_t)g, (lptr_t)l, 16, 0, 0);
}

// -------- workspace layout (floats), total ~28.7M f = 114.7 MB --------
#define WS_XZ     0
#define WS_YTH    8388608
#define WS_YTL    12582912
#define WS_COEF   16777216
#define WS_STATES 16875520
#define WS_LOOK   17924096
#define WS_HH     18186240
#define WS_HL     20283392
#define WS_WIH    22380544
#define WS_WIL    24477696
#define WS_WOH    26574848
#define WS_WOL    27623424

// ============ split f32 -> bf16 hi/lo planes ============
__global__ __launch_bounds__(256) void cvt_split4(const float* __restrict__ s,
                                                  __bf16* __restrict__ h,
                                                  __bf16* __restrict__ l, int n4) {
    int i = blockIdx.x * 256 + threadIdx.x;
    if (i >= n4) return;
    float4 v = ((const float4*)s)[i];
    float vv[4] = {v.x, v.y, v.z, v.w};
    bf16x4 hv, lv;
#pragma unroll
    for (int j = 0; j < 4; ++j) {
        __bf16 hb = (__bf16)vv[j];
        hv[j] = hb;
        lv[j] = (__bf16)(vv[j] - (float)hb);
    }
    *(bf16x4*)&h[(size_t)i * 4] = hv;
    *(bf16x4*)&l[(size_t)i * 4] = lv;
}

// ============ coefficient precompute ============
__global__ void coef_kernel(const float* __restrict__ log_dt,
                            const float* __restrict__ log_A_real,
                            const float* __restrict__ A_imag,
                            const float* __restrict__ C_re,
                            const float* __restrict__ C_im,
                            float* __restrict__ coef) {
    int i = blockIdx.x * blockDim.x + threadIdx.x;
    if (i >= H_DIM * N_ST) return;
    int h = i >> 3;
    float dt = expf(log_dt[h]);
    float Ar = -expf(log_A_real[i]);
    float Ai = A_imag[i];
    float er = expf(dt * Ar);
    float ang = dt * Ai;
    float wr = er * cosf(ang);
    float wi = er * sinf(ang);
    float den = Ar * Ar + Ai * Ai;
    float qr = ((wr - 1.f) * Ar + wi * Ai) / den;
    float qi = (wi * Ar - (wr - 1.f) * Ai) / den;
    float Cr = C_re[i], Ci = C_im[i];
    float Ctr = Cr * qr - Ci * qi;
    float Cti = Cr * qi + Ci * qr;
    float eCL = expf((float)CL * dt * Ar);
    float aCL = (float)CL * dt * Ai;
    float pr = eCL * cosf(aCL);
    float pi = eCL * sinf(aCL);
    const int HN = H_DIM * N_ST;
    coef[i]          = wr;
    coef[HN + i]     = wi;
    coef[2 * HN + i] = Ctr;
    coef[3 * HN + i] = Cti;
    coef[4 * HN + i] = pr;
    coef[5 * HN + i] = pi;
}

// ============ split-bf16 MFMA GEMM (B^T form), T3 2-phase: stage-early, 1 barrier/iter ============
// C[M][N] = sum_k A[m][k]*B[n][k]; C = Ah*Bh + Ah*Bl + Al*Bh (fp32 accum).
// 128x128 tile, 4 waves (2x2), BK=32, LDS double-buffer, 2 blocks/CU.
__global__ __launch_bounds__(256, 2) void gemm_split(const __bf16* __restrict__ Ah,
                                                     const __bf16* __restrict__ Al,
                                                     const __bf16* __restrict__ Bh,
                                                     const __bf16* __restrict__ Bl,
                                                     float* __restrict__ C,
                                                     int K, int ldc) {
    __shared__ __bf16 sAh[2][4096], sAl[2][4096], sBh[2][4096], sBl[2][4096];
    const int tid = threadIdx.x;
    const int lane = tid & 63;
    const int wid = tid >> 6;
    const int wrw = wid >> 1, wcw = wid & 1;
    const int bm = blockIdx.y, bn = blockIdx.x;

    const int r = tid & 127;          // staging row within tile
    const int kbq8 = (tid >> 7) * 8;  // staging kb-oct offset
    const size_t arow = (size_t)(bm * 128 + r) * K;
    const size_t brow = (size_t)(bn * 128 + r) * K;

    f32x4 acc[4][4];
#pragma unroll
    for (int m = 0; m < 4; ++m)
#pragma unroll
        for (int n = 0; n < 4; ++n) acc[m][n] = (f32x4){0.f, 0.f, 0.f, 0.f};

    const int kb = lane >> 4, rr = lane & 15;

    auto stage = [&](int b, int k0) {
#pragma unroll
        for (int q = 0; q < 2; ++q) {
            const int lo = q * 2048 + tid * 8;
            const size_t go = (size_t)k0 + q * 16 + kbq8;
            gl_lds16(Ah + arow + go, &sAh[b][lo]);
            gl_lds16(Al + arow + go, &sAl[b][lo]);
            gl_lds16(Bh + brow + go, &sBh[b][lo]);
            gl_lds16(Bl + brow + go, &sBl[b][lo]);
        }
    };

    const int nt = K >> 5;
    stage(0, 0);
    asm volatile("s_waitcnt vmcnt(0)" ::: "memory");
    __builtin_amdgcn_s_barrier();

    for (int t = 0; t < nt; ++t) {
        const int cur = t & 1;
        // issue next tile's staging first: HBM latency hides under ds_read + MFMA
        if (t + 1 < nt) stage(cur ^ 1, (t + 1) << 5);

        bf16x8 fAh[4], fAl[4], fBh[4], fBl[4];
#pragma unroll
        for (int m = 0; m < 4; ++m) {
            int off = kb * 1024 + (wrw * 64 + m * 16 + rr) * 8;
            fAh[m] = *(const bf16x8*)&sAh[cur][off];
            fAl[m] = *(const bf16x8*)&sAl[cur][off];
        }
#pragma unroll
        for (int n = 0; n < 4; ++n) {
            int off = kb * 1024 + (wcw * 64 + n * 16 + rr) * 8;
            fBh[n] = *(const bf16x8*)&sBh[cur][off];
            fBl[n] = *(const bf16x8*)&sBl[cur][off];
        }
        asm volatile("s_waitcnt lgkmcnt(0)" ::: "memory");
        __builtin_amdgcn_sched_barrier(0);
        __builtin_amdgcn_s_setprio(1);
#pragma unroll
        for (int m = 0; m < 4; ++m)
#pragma unroll
            for (int n = 0; n < 4; ++n) {
                acc[m][n] = __builtin_amdgcn_mfma_f32_16x16x32_bf16(fAh[m], fBh[n], acc[m][n], 0, 0, 0);
                acc[m][n] = __builtin_amdgcn_mfma_f32_16x16x32_bf16(fAh[m], fBl[n], acc[m][n], 0, 0, 0);
                acc[m][n] = __builtin_amdgcn_mfma_f32_16x16x32_bf16(fAl[m], fBh[n], acc[m][n], 0, 0, 0);
            }
        __builtin_amdgcn_s_setprio(0);
        // next tile staged + all waves done reading buf[cur] -> safe to flip
        asm volatile("s_waitcnt vmcnt(0)" ::: "memory");
        __builtin_amdgcn_s_barrier();
    }

    const int rq = lane >> 4;
#pragma unroll
    for (int m = 0; m < 4; ++m)
#pragma unroll
        for (int n = 0; n < 4; ++n) {
            int col = bn * 128 + wcw * 64 + n * 16 + rr;
            int row0 = bm * 128 + wrw * 64 + m * 16 + rq * 4;
#pragma unroll
            for (int j = 0; j < 4; ++j)
                C[(size_t)(row0 + j) * ldc + col] = acc[m][n][j];
        }
}

// ============ scan phase 1: local chunk scans (fused conv+SiLU) ============
__global__ __launch_bounds__(256) void scan_phase1(const float* __restrict__ xz,
                                                   const float* __restrict__ coef,
                                                   const float* __restrict__ conv_w,
                                                   const float* __restrict__ conv_b,
                                                   float* __restrict__ states,
                                                   float* __restrict__ look) {
    int t = blockIdx.x * 256 + threadIdx.x;   // t = h*NC + c
    int c = t & (NC - 1);
    int h = t >> 5;

    const int HN = H_DIM * N_ST;
    float wr[N_ST], wi[N_ST];
#pragma unroll
    for (int n = 0; n < N_ST; ++n) {
        wr[n] = coef[h * N_ST + n];
        wi[n] = coef[HN + h * N_ST + n];
    }
    float cw0 = conv_w[h * 4 + 0], cw1 = conv_w[h * 4 + 1];
    float cw2 = conv_w[h * 4 + 2], cw3 = conv_w[h * 4 + 3];
    float cb = conv_b[h];

    const float* xrow = xz + (size_t)h * L_SEQ + c * CL;
    float x3 = 0.f, x2 = 0.f, x1 = 0.f;
    if (c > 0) {
        float4 p = *(const float4*)(xrow - 4);
        x3 = p.y; x2 = p.z; x1 = p.w;
    }
    *(float4*)(look + (size_t)t * 4) = make_float4(x3, x2, x1, 0.f);

    float sr[N_ST], si[N_ST];
#pragma unroll
    for (int n = 0; n < N_ST; ++n) { sr[n] = 0.f; si[n] = 0.f; }

    for (int j = 0; j < CL; j += 4) {
        float4 v = *(const float4*)(xrow + j);
        float xv[4] = {v.x, v.y, v.z, v.w};
#pragma unroll
        for (int k = 0; k < 4; ++k) {
            float u = cw0 * x3 + cw1 * x2 + cw2 * x1 + cw3 * xv[k] + cb;
            float xc = u / (1.f + __expf(-u));
            x3 = x2; x2 = x1; x1 = xv[k];
#pragma unroll
            for (int n = 0; n < N_ST; ++n) {
                float nr = wr[n] * sr[n] - wi[n] * si[n] + xc;
                float ni = wr[n] * si[n] + wi[n] * sr[n];
                sr[n] = nr; si[n] = ni;
            }
        }
    }
    float* st = states + (size_t)t * (N_ST * 2);
#pragma unroll
    for (int n = 0; n < N_ST; ++n) { st[2 * n] = sr[n]; st[2 * n + 1] = si[n]; }
}

// ============ scan phase 2: combine chunk states -> chunk init states ============
__global__ __launch_bounds__(256) void scan_phase2(const float* __restrict__ coef,
                                                   float* __restrict__ states) {
    int h = blockIdx.x * 256 + threadIdx.x;
    if (h >= H_DIM) return;
    const int HN = H_DIM * N_ST;
    float pr[N_ST], pi[N_ST];
#pragma unroll
    for (int n = 0; n < N_ST; ++n) {
        pr[n] = coef[4 * HN + h * N_ST + n];
        pi[n] = coef[5 * HN + h * N_ST + n];
    }
    float sr[N_ST], si[N_ST];
#pragma unroll
    for (int n = 0; n < N_ST; ++n) { sr[n] = 0.f; si[n] = 0.f; }
    float* base = states + (size_t)h * NC * (N_ST * 2);
    for (int c = 0; c < NC; ++c) {
        float* st = base + c * (N_ST * 2);
#pragma unroll
        for (int n = 0; n < N_ST; ++n) {
            float lr = st[2 * n], li = st[2 * n + 1];
            st[2 * n] = sr[n]; st[2 * n + 1] = si[n];
            float nr = pr[n] * sr[n] - pi[n] * si[n] + lr;
            float ni = pr[n] * si[n] + pi[n] * sr[n] + li;
            sr[n] = nr; si[n] = ni;
        }
    }
}

// ============ scan phase 3: replay, fused D-skip + gate; writes y f32 OVER x ============
__global__ __launch_bounds__(256) void scan_phase3(float* __restrict__ xz,
                                                   const float* __restrict__ coef,
                                                   const float* __restrict__ conv_w,
                                                   const float* __restrict__ conv_b,
                                                   const float* __restrict__ Dvec,
                                                   const float* __restrict__ states,
                                                   const float* __restrict__ look) {
    int t = blockIdx.x * 256 + threadIdx.x;
    int c = t & (NC - 1);
    int h = t >> 5;

    const int HN = H_DIM * N_ST;
    float wr[N_ST], wi[N_ST], Ctr[N_ST], Cti[N_ST];
#pragma unroll
    for (int n = 0; n < N_ST; ++n) {
        wr[n]  = coef[h * N_ST + n];
        wi[n]  = coef[HN + h * N_ST + n];
        Ctr[n] = coef[2 * HN + h * N_ST + n];
        Cti[n] = coef[3 * HN + h * N_ST + n];
    }
    float cw0 = conv_w[h * 4 + 0], cw1 = conv_w[h * 4 + 1];
    float cw2 = conv_w[h * 4 + 2], cw3 = conv_w[h * 4 + 3];
    float cb = conv_b[h];
    float Dh = Dvec[h];

    float* xrow = xz + (size_t)h * L_SEQ + c * CL;
    const float* zrow = xz + (size_t)(H_DIM + h) * L_SEQ + c * CL;

    float4 lk = *(const float4*)(look + (size_t)t * 4);
    float x3 = lk.x, x2 = lk.y, x1 = lk.z;

    const float* st = states + (size_t)t * (N_ST * 2);
    float sr[N_ST], si[N_ST];
#pragma unroll
    for (int n = 0; n < N_ST; ++n) { sr[n] = st[2 * n]; si[n] = st[2 * n + 1]; }

    for (int j = 0; j < CL; j += 4) {
        float4 v = *(const float4*)(xrow + j);
        float4 zv = *(const float4*)(zrow + j);
        float xv[4] = {v.x, v.y, v.z, v.w};
        float zz[4] = {zv.x, zv.y, zv.z, zv.w};
        float out[4];
#pragma unroll
        for (int k = 0; k < 4; ++k) {
            float u = cw0 * x3 + cw1 * x2 + cw2 * x1 + cw3 * xv[k] + cb;
            float xc = u / (1.f + __expf(-u));
            x3 = x2; x2 = x1; x1 = xv[k];
            float accy = 0.f;
#pragma unroll
            for (int n = 0; n < N_ST; ++n) {
                float nr = wr[n] * sr[n] - wi[n] * si[n] + xc;
                float ni = wr[n] * si[n] + wi[n] * sr[n];
                sr[n] = nr; si[n] = ni;
                accy += Ctr[n] * nr - Cti[n] * ni;
            }
            float yv = 2.f * accy + Dh * xc;
            float g = zz[k] / (1.f + __expf(-zz[k]));
            out[k] = yv * g;
        }
        *(float4*)(xrow + j) = make_float4(out[0], out[1], out[2], out[3]);
    }
}

// ============ transpose + split: y f32 [H][L] -> yTh/yTl bf16 [L][H] ============
__global__ __launch_bounds__(256) void transpose_split(const float* __restrict__ y,
                                                       __bf16* __restrict__ th,
                                                       __bf16* __restrict__ tl) {
    __shared__ float tile[64][65];
    const int l0 = blockIdx.x * 64, h0 = blockIdx.y * 64;
    const int tid = threadIdx.x;
    const int r = tid >> 4, c4 = (tid & 15) * 4;
#pragma unroll
    for (int p = 0; p < 4; ++p) {
        float4 v = *(const float4*)(y + (size_t)(h0 + r + p * 16) * L_SEQ + l0 + c4);
        tile[r + p * 16][c4 + 0] = v.x;
        tile[r + p * 16][c4 + 1] = v.y;
        tile[r + p * 16][c4 + 2] = v.z;
        tile[r + p * 16][c4 + 3] = v.w;
    }
    __syncthreads();
    const int l = tid >> 2, hb = (tid & 3) * 16;
    float vals[16];
#pragma unroll
    for (int j = 0; j < 16; ++j) vals[j] = tile[hb + j][l];
    bf16x8 hv0, hv1, lv0, lv1;
#pragma unroll
    for (int j = 0; j < 8; ++j) {
        __bf16 hbv = (__bf16)vals[j];
        hv0[j] = hbv;
        lv0[j] = (__bf16)(vals[j] - (float)hbv);
        __bf16 hbv2 = (__bf16)vals[j + 8];
        hv1[j] = hbv2;
        lv1[j] = (__bf16)(vals[j + 8] - (float)hbv2);
    }
    size_t base = (size_t)(l0 + l) * H_DIM + h0 + hb;
    *(bf16x8*)&th[base] = hv0;
    *(bf16x8*)&th[base + 8] = hv1;
    *(bf16x8*)&tl[base] = lv0;
    *(bf16x8*)&tl[base + 8] = lv1;
}

extern "C" void kernel_launch(void* const* d_in, const int* in_sizes, int n_in,
                              void* d_out, int out_size, void* d_ws, size_t ws_size,
                              hipStream_t stream) {
    const float* hid        = (const float*)d_in[0];
    const float* W_in       = (const float*)d_in[1];
    const float* conv_w     = (const float*)d_in[2];
    const float* conv_b     = (const float*)d_in[3];
    const float* log_dt     = (const float*)d_in[4];
    const float* log_A_real = (const float*)d_in[5];
    const float* A_imag     = (const float*)d_in[6];
    const float* C_re       = (const float*)d_in[7];
    const float* C_im       = (const float*)d_in[8];
    const float* Dv         = (const float*)d_in[9];
    const float* W_out      = (const float*)d_in[10];
    float* out = (float*)d_out;
    float* ws  = (float*)d_ws;

    float* xz      = ws + WS_XZ;
    __bf16* yTh    = (__bf16*)(ws + WS_YTH);
    __bf16* yTl    = (__bf16*)(ws + WS_YTL);
    float* coef    = ws + WS_COEF;
    float* states  = ws + WS_STATES;
    float* look    = ws + WS_LOOK;
    __bf16* Hh     = (__bf16*)(ws + WS_HH);
    __bf16* Hl     = (__bf16*)(ws + WS_HL);
    __bf16* Wih    = (__bf16*)(ws + WS_WIH);
    __bf16* Wil    = (__bf16*)(ws + WS_WIL);
    __bf16* Woh    = (__bf16*)(ws + WS_WOH);
    __bf16* Wol    = (__bf16*)(ws + WS_WOL);

    coef_kernel<<<(H_DIM * N_ST + 255) / 256, 256, 0, stream>>>(
        log_dt, log_A_real, A_imag, C_re, C_im, coef);

    cvt_split4<<<(2 * H_DIM * DMODEL / 4 + 255) / 256, 256, 0, stream>>>(W_in, Wih, Wil, 2 * H_DIM * DMODEL / 4);
    cvt_split4<<<(DMODEL * H_DIM / 4 + 255) / 256, 256, 0, stream>>>(W_out, Woh, Wol, DMODEL * H_DIM / 4);

    const int nscan = H_DIM * NC;            // 65536
    dim3 gIn(L_SEQ / 128, 2 * H_DIM / 128);  // (32,32)
    dim3 gOut(DMODEL / 128, L_SEQ / 128);    // (8,32)
    dim3 gTr(L_SEQ / 64, H_DIM / 64);        // (64,32)

    for (int b = 0; b < B_SZ; ++b) {
        const float* hid_b = hid + (size_t)b * L_SEQ * DMODEL;
        float* out_b = out + (size_t)b * L_SEQ * DMODEL;

        cvt_split4<<<(L_SEQ * DMODEL / 4 + 255) / 256, 256, 0, stream>>>(hid_b, Hh, Hl, L_SEQ * DMODEL / 4);
        gemm_split<<<gIn, 256, 0, stream>>>(Wih, Wil, Hh, Hl, xz, DMODEL, L_SEQ);
        scan_phase1<<<nscan / 256, 256, 0, stream>>>(xz, coef, conv_w, conv_b, states, look);
        scan_phase2<<<(H_DIM + 255) / 256, 256, 0, stream>>>(coef, states);
        scan_phase3<<<nscan / 256, 256, 0, stream>>>(xz, coef, conv_w, conv_b, Dv, states, look);
        transpose_split<<<gTr, 256, 0, stream>>>(xz, yTh, yTl);
        gemm_split<<<gOut, 256, 0, stream>>>(yTh, yTl, Woh, Wol, out_b, H_DIM, DMODEL);
    }
}

// Round 6
// 1631.624 us; speedup vs baseline: 1.0464x; 1.0426x over previous
//
#include <hip/hip_runtime.h>
#include <hip/hip_bf16.h>
#include <math.h>

#define H_DIM 2048
#define N_ST 8
#define B_SZ 4
#define L_SEQ 4096
#define DMODEL 1024
#define DCONV 4
#define CL 128
#define NC (L_SEQ / CL)   // 32

typedef __bf16 bf16x8 __attribute__((ext_vector_type(8)));
typedef __bf16 bf16x4 __attribute__((ext_vector_type(4)));
typedef float f32x4 __attribute__((ext_vector_type(4)));

typedef const unsigned int __attribute__((address_space(1)))* gptr_t;
typedef unsigned int __attribute__((address_space(3)))* lptr_t;

__device__ __forceinline__ void gl_lds16(const __bf16* g, __bf16* l) {
    __builtin_amdgcn_global_load_lds((gptr_t)g, (lptr_t)l, 16, 0, 0);
}

// -------- workspace layout (floats), total ~28.7M f = 114.7 MB --------
#define WS_XZ     0
#define WS_YTH    8388608
#define WS_YTL    12582912
#define WS_COEF   16777216
#define WS_STATES 16875520
#define WS_LOOK   17924096
#define WS_HH     18186240
#define WS_HL     20283392
#define WS_WIH    22380544
#define WS_WIL    24477696
#define WS_WOH    26574848
#define WS_WOL    27623424

// ============ split f32 -> bf16 hi/lo planes ============
__global__ __launch_bounds__(256) void cvt_split4(const float* __restrict__ s,
                                                  __bf16* __restrict__ h,
                                                  __bf16* __restrict__ l, int n4) {
    int i = blockIdx.x * 256 + threadIdx.x;
    if (i >= n4) return;
    float4 v = ((const float4*)s)[i];
    float vv[4] = {v.x, v.y, v.z, v.w};
    bf16x4 hv, lv;
#pragma unroll
    for (int j = 0; j < 4; ++j) {
        __bf16 hb = (__bf16)vv[j];
        hv[j] = hb;
        lv[j] = (__bf16)(vv[j] - (float)hb);
    }
    *(bf16x4*)&h[(size_t)i * 4] = hv;
    *(bf16x4*)&l[(size_t)i * 4] = lv;
}

// ============ coefficient precompute ============
__global__ void coef_kernel(const float* __restrict__ log_dt,
                            const float* __restrict__ log_A_real,
                            const float* __restrict__ A_imag,
                            const float* __restrict__ C_re,
                            const float* __restrict__ C_im,
                            float* __restrict__ coef) {
    int i = blockIdx.x * blockDim.x + threadIdx.x;
    if (i >= H_DIM * N_ST) return;
    int h = i >> 3;
    float dt = expf(log_dt[h]);
    float Ar = -expf(log_A_real[i]);
    float Ai = A_imag[i];
    float er = expf(dt * Ar);
    float ang = dt * Ai;
    float wr = er * cosf(ang);
    float wi = er * sinf(ang);
    float den = Ar * Ar + Ai * Ai;
    float qr = ((wr - 1.f) * Ar + wi * Ai) / den;
    float qi = (wi * Ar - (wr - 1.f) * Ai) / den;
    float Cr = C_re[i], Ci = C_im[i];
    float Ctr = Cr * qr - Ci * qi;
    float Cti = Cr * qi + Ci * qr;
    float eCL = expf((float)CL * dt * Ar);
    float aCL = (float)CL * dt * Ai;
    float pr = eCL * cosf(aCL);
    float pi = eCL * sinf(aCL);
    const int HN = H_DIM * N_ST;
    coef[i]          = wr;
    coef[HN + i]     = wi;
    coef[2 * HN + i] = Ctr;
    coef[3 * HN + i] = Cti;
    coef[4 * HN + i] = pr;
    coef[5 * HN + i] = pi;
}

// ============ split-bf16 MFMA GEMM (B^T form), depth-2 prefetch + counted vmcnt ============
// C[M][N] = sum_k A[m][k]*B[n][k]; C = Ah*Bh + Ah*Bl + Al*Bh (fp32 accum).
// 128x128 tile, 4 waves (2x2), BK=32, 2 LDS buffers; tile t+2 refills the buffer
// tile t just vacated, so vmcnt(8) (= tile t+1 landed) never drains the queue.
__global__ __launch_bounds__(256, 2) void gemm_split(const __bf16* __restrict__ Ah,
                                                     const __bf16* __restrict__ Al,
                                                     const __bf16* __restrict__ Bh,
                                                     const __bf16* __restrict__ Bl,
                                                     float* __restrict__ C,
                                                     int K, int ldc) {
    __shared__ __bf16 sAh[2][4096], sAl[2][4096], sBh[2][4096], sBl[2][4096];
    const int tid = threadIdx.x;
    const int lane = tid & 63;
    const int wid = tid >> 6;
    const int wrw = wid >> 1, wcw = wid & 1;
    const int bm = blockIdx.y, bn = blockIdx.x;

    const int r = tid & 127;          // staging row within tile
    const int kbq8 = (tid >> 7) * 8;  // staging kb-oct offset
    const size_t arow = (size_t)(bm * 128 + r) * K;
    const size_t brow = (size_t)(bn * 128 + r) * K;

    f32x4 acc[4][4];
#pragma unroll
    for (int m = 0; m < 4; ++m)
#pragma unroll
        for (int n = 0; n < 4; ++n) acc[m][n] = (f32x4){0.f, 0.f, 0.f, 0.f};

    const int kb = lane >> 4, rr = lane & 15;

    auto stage = [&](int b, int k0) {
#pragma unroll
        for (int q = 0; q < 2; ++q) {
            const int lo = q * 2048 + tid * 8;
            const size_t go = (size_t)k0 + q * 16 + kbq8;
            gl_lds16(Ah + arow + go, &sAh[b][lo]);
            gl_lds16(Al + arow + go, &sAl[b][lo]);
            gl_lds16(Bh + brow + go, &sBh[b][lo]);
            gl_lds16(Bl + brow + go, &sBl[b][lo]);
        }
    };

    const int nt = K >> 5;
    stage(0, 0);
    stage(1, 32);
    // tile 0 landed (8 oldest); tile 1's 8 stay in flight
    asm volatile("s_waitcnt vmcnt(8)" ::: "memory");
    __builtin_amdgcn_s_barrier();

    for (int t = 0; t < nt; ++t) {
        const int cur = t & 1;

        // 1. read this tile's fragments from LDS
        bf16x8 fAh[4], fAl[4], fBh[4], fBl[4];
#pragma unroll
        for (int m = 0; m < 4; ++m) {
            int off = kb * 1024 + (wrw * 64 + m * 16 + rr) * 8;
            fAh[m] = *(const bf16x8*)&sAh[cur][off];
            fAl[m] = *(const bf16x8*)&sAl[cur][off];
        }
#pragma unroll
        for (int n = 0; n < 4; ++n) {
            int off = kb * 1024 + (wcw * 64 + n * 16 + rr) * 8;
            fBh[n] = *(const bf16x8*)&sBh[cur][off];
            fBl[n] = *(const bf16x8*)&sBl[cur][off];
        }
        // 2. own reads complete (regs hold data)
        asm volatile("s_waitcnt lgkmcnt(0)" ::: "memory");
        __builtin_amdgcn_sched_barrier(0);
        // 3. all waves done reading buf[cur] -> safe to refill it
        __builtin_amdgcn_s_barrier();
        __builtin_amdgcn_sched_barrier(0);
        // 4. refill buf[cur] with tile t+2 (overlaps MFMA below + next iter's ds_read)
        if (t + 2 < nt) stage(cur, (t + 2) << 5);
        // 5. compute
        __builtin_amdgcn_s_setprio(1);
#pragma unroll
        for (int m = 0; m < 4; ++m)
#pragma unroll
            for (int n = 0; n < 4; ++n) {
                acc[m][n] = __builtin_amdgcn_mfma_f32_16x16x32_bf16(fAh[m], fBh[n], acc[m][n], 0, 0, 0);
                acc[m][n] = __builtin_amdgcn_mfma_f32_16x16x32_bf16(fAh[m], fBl[n], acc[m][n], 0, 0, 0);
                acc[m][n] = __builtin_amdgcn_mfma_f32_16x16x32_bf16(fAl[m], fBh[n], acc[m][n], 0, 0, 0);
            }
        __builtin_amdgcn_s_setprio(0);
        // 6. tile t+1 landed (its 8 loads are oldest); tile t+2 stays in flight
        if (t + 2 < nt) asm volatile("s_waitcnt vmcnt(8)" ::: "memory");
        else            asm volatile("s_waitcnt vmcnt(0)" ::: "memory");
        __builtin_amdgcn_s_barrier();
    }

    const int rq = lane >> 4;
#pragma unroll
    for (int m = 0; m < 4; ++m)
#pragma unroll
        for (int n = 0; n < 4; ++n) {
            int col = bn * 128 + wcw * 64 + n * 16 + rr;
            int row0 = bm * 128 + wrw * 64 + m * 16 + rq * 4;
#pragma unroll
            for (int j = 0; j < 4; ++j)
                C[(size_t)(row0 + j) * ldc + col] = acc[m][n][j];
        }
}

// ============ scan phase 1: local chunk scans (fused conv+SiLU) ============
__global__ __launch_bounds__(256) void scan_phase1(const float* __restrict__ xz,
                                                   const float* __restrict__ coef,
                                                   const float* __restrict__ conv_w,
                                                   const float* __restrict__ conv_b,
                                                   float* __restrict__ states,
                                                   float* __restrict__ look) {
    int t = blockIdx.x * 256 + threadIdx.x;   // t = h*NC + c
    int c = t & (NC - 1);
    int h = t >> 5;

    const int HN = H_DIM * N_ST;
    float wr[N_ST], wi[N_ST];
#pragma unroll
    for (int n = 0; n < N_ST; ++n) {
        wr[n] = coef[h * N_ST + n];
        wi[n] = coef[HN + h * N_ST + n];
    }
    float cw0 = conv_w[h * 4 + 0], cw1 = conv_w[h * 4 + 1];
    float cw2 = conv_w[h * 4 + 2], cw3 = conv_w[h * 4 + 3];
    float cb = conv_b[h];

    const float* xrow = xz + (size_t)h * L_SEQ + c * CL;
    float x3 = 0.f, x2 = 0.f, x1 = 0.f;
    if (c > 0) {
        float4 p = *(const float4*)(xrow - 4);
        x3 = p.y; x2 = p.z; x1 = p.w;
    }
    *(float4*)(look + (size_t)t * 4) = make_float4(x3, x2, x1, 0.f);

    float sr[N_ST], si[N_ST];
#pragma unroll
    for (int n = 0; n < N_ST; ++n) { sr[n] = 0.f; si[n] = 0.f; }

    for (int j = 0; j < CL; j += 4) {
        float4 v = *(const float4*)(xrow + j);
        float xv[4] = {v.x, v.y, v.z, v.w};
#pragma unroll
        for (int k = 0; k < 4; ++k) {
            float u = cw0 * x3 + cw1 * x2 + cw2 * x1 + cw3 * xv[k] + cb;
            float xc = u / (1.f + __expf(-u));
            x3 = x2; x2 = x1; x1 = xv[k];
#pragma unroll
            for (int n = 0; n < N_ST; ++n) {
                float nr = wr[n] * sr[n] - wi[n] * si[n] + xc;
                float ni = wr[n] * si[n] + wi[n] * sr[n];
                sr[n] = nr; si[n] = ni;
            }
        }
    }
    float* st = states + (size_t)t * (N_ST * 2);
#pragma unroll
    for (int n = 0; n < N_ST; ++n) { st[2 * n] = sr[n]; st[2 * n + 1] = si[n]; }
}

// ============ scan phase 2: combine chunk states -> chunk init states ============
__global__ __launch_bounds__(256) void scan_phase2(const float* __restrict__ coef,
                                                   float* __restrict__ states) {
    int h = blockIdx.x * 256 + threadIdx.x;
    if (h >= H_DIM) return;
    const int HN = H_DIM * N_ST;
    float pr[N_ST], pi[N_ST];
#pragma unroll
    for (int n = 0; n < N_ST; ++n) {
        pr[n] = coef[4 * HN + h * N_ST + n];
        pi[n] = coef[5 * HN + h * N_ST + n];
    }
    float sr[N_ST], si[N_ST];
#pragma unroll
    for (int n = 0; n < N_ST; ++n) { sr[n] = 0.f; si[n] = 0.f; }
    float* base = states + (size_t)h * NC * (N_ST * 2);
    for (int c = 0; c < NC; ++c) {
        float* st = base + c * (N_ST * 2);
#pragma unroll
        for (int n = 0; n < N_ST; ++n) {
            float lr = st[2 * n], li = st[2 * n + 1];
            st[2 * n] = sr[n]; st[2 * n + 1] = si[n];
            float nr = pr[n] * sr[n] - pi[n] * si[n] + lr;
            float ni = pr[n] * si[n] + pi[n] * sr[n] + li;
            sr[n] = nr; si[n] = ni;
        }
    }
}

// ============ scan phase 3: replay, fused D-skip + gate; writes y f32 OVER x ============
__global__ __launch_bounds__(256) void scan_phase3(float* __restrict__ xz,
                                                   const float* __restrict__ coef,
                                                   const float* __restrict__ conv_w,
                                                   const float* __restrict__ conv_b,
                                                   const float* __restrict__ Dvec,
                                                   const float* __restrict__ states,
                                                   const float* __restrict__ look) {
    int t = blockIdx.x * 256 + threadIdx.x;
    int c = t & (NC - 1);
    int h = t >> 5;

    const int HN = H_DIM * N_ST;
    float wr[N_ST], wi[N_ST], Ctr[N_ST], Cti[N_ST];
#pragma unroll
    for (int n = 0; n < N_ST; ++n) {
        wr[n]  = coef[h * N_ST + n];
        wi[n]  = coef[HN + h * N_ST + n];
        Ctr[n] = coef[2 * HN + h * N_ST + n];
        Cti[n] = coef[3 * HN + h * N_ST + n];
    }
    float cw0 = conv_w[h * 4 + 0], cw1 = conv_w[h * 4 + 1];
    float cw2 = conv_w[h * 4 + 2], cw3 = conv_w[h * 4 + 3];
    float cb = conv_b[h];
    float Dh = Dvec[h];

    float* xrow = xz + (size_t)h * L_SEQ + c * CL;
    const float* zrow = xz + (size_t)(H_DIM + h) * L_SEQ + c * CL;

    float4 lk = *(const float4*)(look + (size_t)t * 4);
    float x3 = lk.x, x2 = lk.y, x1 = lk.z;

    const float* st = states + (size_t)t * (N_ST * 2);
    float sr[N_ST], si[N_ST];
#pragma unroll
    for (int n = 0; n < N_ST; ++n) { sr[n] = st[2 * n]; si[n] = st[2 * n + 1]; }

    for (int j = 0; j < CL; j += 4) {
        float4 v = *(const float4*)(xrow + j);
        float4 zv = *(const float4*)(zrow + j);
        float xv[4] = {v.x, v.y, v.z, v.w};
        float zz[4] = {zv.x, zv.y, zv.z, zv.w};
        float out[4];
#pragma unroll
        for (int k = 0; k < 4; ++k) {
            float u = cw0 * x3 + cw1 * x2 + cw2 * x1 + cw3 * xv[k] + cb;
            float xc = u / (1.f + __expf(-u));
            x3 = x2; x2 = x1; x1 = xv[k];
            float accy = 0.f;
#pragma unroll
            for (int n = 0; n < N_ST; ++n) {
                float nr = wr[n] * sr[n] - wi[n] * si[n] + xc;
                float ni = wr[n] * si[n] + wi[n] * sr[n];
                sr[n] = nr; si[n] = ni;
                accy += Ctr[n] * nr - Cti[n] * ni;
            }
            float yv = 2.f * accy + Dh * xc;
            float g = zz[k] / (1.f + __expf(-zz[k]));
            out[k] = yv * g;
        }
        *(float4*)(xrow + j) = make_float4(out[0], out[1], out[2], out[3]);
    }
}

// ============ transpose + split: y f32 [H][L] -> yTh/yTl bf16 [L][H] ============
__global__ __launch_bounds__(256) void transpose_split(const float* __restrict__ y,
                                                       __bf16* __restrict__ th,
                                                       __bf16* __restrict__ tl) {
    __shared__ float tile[64][65];
    const int l0 = blockIdx.x * 64, h0 = blockIdx.y * 64;
    const int tid = threadIdx.x;
    const int r = tid >> 4, c4 = (tid & 15) * 4;
#pragma unroll
    for (int p = 0; p < 4; ++p) {
        float4 v = *(const float4*)(y + (size_t)(h0 + r + p * 16) * L_SEQ + l0 + c4);
        tile[r + p * 16][c4 + 0] = v.x;
        tile[r + p * 16][c4 + 1] = v.y;
        tile[r + p * 16][c4 + 2] = v.z;
        tile[r + p * 16][c4 + 3] = v.w;
    }
    __syncthreads();
    const int l = tid >> 2, hb = (tid & 3) * 16;
    float vals[16];
#pragma unroll
    for (int j = 0; j < 16; ++j) vals[j] = tile[hb + j][l];
    bf16x8 hv0, hv1, lv0, lv1;
#pragma unroll
    for (int j = 0; j < 8; ++j) {
        __bf16 hbv = (__bf16)vals[j];
        hv0[j] = hbv;
        lv0[j] = (__bf16)(vals[j] - (float)hbv);
        __bf16 hbv2 = (__bf16)vals[j + 8];
        hv1[j] = hbv2;
        lv1[j] = (__bf16)(vals[j + 8] - (float)hbv2);
    }
    size_t base = (size_t)(l0 + l) * H_DIM + h0 + hb;
    *(bf16x8*)&th[base] = hv0;
    *(bf16x8*)&th[base + 8] = hv1;
    *(bf16x8*)&tl[base] = lv0;
    *(bf16x8*)&tl[base + 8] = lv1;
}

extern "C" void kernel_launch(void* const* d_in, const int* in_sizes, int n_in,
                              void* d_out, int out_size, void* d_ws, size_t ws_size,
                              hipStream_t stream) {
    const float* hid        = (const float*)d_in[0];
    const float* W_in       = (const float*)d_in[1];
    const float* conv_w     = (const float*)d_in[2];
    const float* conv_b     = (const float*)d_in[3];
    const float* log_dt     = (const float*)d_in[4];
    const float* log_A_real = (const float*)d_in[5];
    const float* A_imag     = (const float*)d_in[6];
    const float* C_re       = (const float*)d_in[7];
    const float* C_im       = (const float*)d_in[8];
    const float* Dv         = (const float*)d_in[9];
    const float* W_out      = (const float*)d_in[10];
    float* out = (float*)d_out;
    float* ws  = (float*)d_ws;

    float* xz      = ws + WS_XZ;
    __bf16* yTh    = (__bf16*)(ws + WS_YTH);
    __bf16* yTl    = (__bf16*)(ws + WS_YTL);
    float* coef    = ws + WS_COEF;
    float* states  = ws + WS_STATES;
    float* look    = ws + WS_LOOK;
    __bf16* Hh     = (__bf16*)(ws + WS_HH);
    __bf16* Hl     = (__bf16*)(ws + WS_HL);
    __bf16* Wih    = (__bf16*)(ws + WS_WIH);
    __bf16* Wil    = (__bf16*)(ws + WS_WIL);
    __bf16* Woh    = (__bf16*)(ws + WS_WOH);
    __bf16* Wol    = (__bf16*)(ws + WS_WOL);

    coef_kernel<<<(H_DIM * N_ST + 255) / 256, 256, 0, stream>>>(
        log_dt, log_A_real, A_imag, C_re, C_im, coef);

    cvt_split4<<<(2 * H_DIM * DMODEL / 4 + 255) / 256, 256, 0, stream>>>(W_in, Wih, Wil, 2 * H_DIM * DMODEL / 4);
    cvt_split4<<<(DMODEL * H_DIM / 4 + 255) / 256, 256, 0, stream>>>(W_out, Woh, Wol, DMODEL * H_DIM / 4);

    const int nscan = H_DIM * NC;            // 65536
    dim3 gIn(L_SEQ / 128, 2 * H_DIM / 128);  // (32,32)
    dim3 gOut(DMODEL / 128, L_SEQ / 128);    // (8,32)
    dim3 gTr(L_SEQ / 64, H_DIM / 64);        // (64,32)

    for (int b = 0; b < B_SZ; ++b) {
        const float* hid_b = hid + (size_t)b * L_SEQ * DMODEL;
        float* out_b = out + (size_t)b * L_SEQ * DMODEL;

        cvt_split4<<<(L_SEQ * DMODEL / 4 + 255) / 256, 256, 0, stream>>>(hid_b, Hh, Hl, L_SEQ * DMODEL / 4);
        gemm_split<<<gIn, 256, 0, stream>>>(Wih, Wil, Hh, Hl, xz, DMODEL, L_SEQ);
        scan_phase1<<<nscan / 256, 256, 0, stream>>>(xz, coef, conv_w, conv_b, states, look);
        scan_phase2<<<(H_DIM + 255) / 256, 256, 0, stream>>>(coef, states);
        scan_phase3<<<nscan / 256, 256, 0, stream>>>(xz, coef, conv_w, conv_b, Dv, states, look);
        transpose_split<<<gTr, 256, 0, stream>>>(xz, yTh, yTl);
        gemm_split<<<gOut, 256, 0, stream>>>(yTh, yTl, Woh, Wol, out_b, H_DIM, DMODEL);
    }
}

// Round 7
// 1602.669 us; speedup vs baseline: 1.0653x; 1.0181x over previous
//
#include <hip/hip_runtime.h>
#include <hip/hip_bf16.h>
#include <math.h>

#define H_DIM 2048
#define N_ST 8
#define B_SZ 4
#define L_SEQ 4096
#define DMODEL 1024
#define DCONV 4
#define CL 128
#define NC (L_SEQ / CL)   // 32

typedef __bf16 bf16x8 __attribute__((ext_vector_type(8)));
typedef __bf16 bf16x4 __attribute__((ext_vector_type(4)));
typedef float f32x4 __attribute__((ext_vector_type(4)));

typedef const unsigned int __attribute__((address_space(1)))* gptr_t;
typedef unsigned int __attribute__((address_space(3)))* lptr_t;

__device__ __forceinline__ void gl_lds16(const __bf16* g, __bf16* l) {
    __builtin_amdgcn_global_load_lds((gptr_t)g, (lptr_t)l, 16, 0, 0);
}

// -------- workspace layout (floats), total ~28.7M f = 114.7 MB --------
#define WS_XZ     0
#define WS_YTH    8388608
#define WS_YTL    12582912
#define WS_COEF   16777216
#define WS_STATES 16875520
#define WS_LOOK   17924096
#define WS_HH     18186240
#define WS_HL     20283392
#define WS_WIH    22380544
#define WS_WIL    24477696
#define WS_WOH    26574848
#define WS_WOL    27623424

// ============ split f32 -> bf16 hi/lo planes ============
__global__ __launch_bounds__(256) void cvt_split4(const float* __restrict__ s,
                                                  __bf16* __restrict__ h,
                                                  __bf16* __restrict__ l, int n4) {
    int i = blockIdx.x * 256 + threadIdx.x;
    if (i >= n4) return;
    float4 v = ((const float4*)s)[i];
    float vv[4] = {v.x, v.y, v.z, v.w};
    bf16x4 hv, lv;
#pragma unroll
    for (int j = 0; j < 4; ++j) {
        __bf16 hb = (__bf16)vv[j];
        hv[j] = hb;
        lv[j] = (__bf16)(vv[j] - (float)hb);
    }
    *(bf16x4*)&h[(size_t)i * 4] = hv;
    *(bf16x4*)&l[(size_t)i * 4] = lv;
}

// ============ coefficient precompute ============
__global__ void coef_kernel(const float* __restrict__ log_dt,
                            const float* __restrict__ log_A_real,
                            const float* __restrict__ A_imag,
                            const float* __restrict__ C_re,
                            const float* __restrict__ C_im,
                            float* __restrict__ coef) {
    int i = blockIdx.x * blockDim.x + threadIdx.x;
    if (i >= H_DIM * N_ST) return;
    int h = i >> 3;
    float dt = expf(log_dt[h]);
    float Ar = -expf(log_A_real[i]);
    float Ai = A_imag[i];
    float er = expf(dt * Ar);
    float ang = dt * Ai;
    float wr = er * cosf(ang);
    float wi = er * sinf(ang);
    float den = Ar * Ar + Ai * Ai;
    float qr = ((wr - 1.f) * Ar + wi * Ai) / den;
    float qi = (wi * Ar - (wr - 1.f) * Ai) / den;
    float Cr = C_re[i], Ci = C_im[i];
    float Ctr = Cr * qr - Ci * qi;
    float Cti = Cr * qi + Ci * qr;
    float eCL = expf((float)CL * dt * Ar);
    float aCL = (float)CL * dt * Ai;
    float pr = eCL * cosf(aCL);
    float pi = eCL * sinf(aCL);
    const int HN = H_DIM * N_ST;
    coef[i]          = wr;
    coef[HN + i]     = wi;
    coef[2 * HN + i] = Ctr;
    coef[3 * HN + i] = Cti;
    coef[4 * HN + i] = pr;
    coef[5 * HN + i] = pi;
}

// ============ 256x256 phased split-bf16 MFMA GEMM (B^T form) ============
// C[M][N] = sum_k A[m][k]*B[n][k]; C = Ah*Bh + Ah*Bl + Al*Bh (fp32 accum).
// BM=BN=256, BK=32, 8 waves (2Mx4N), per-wave 128x64. LDS 128 KiB (2 bufs).
// 4 phases/K-tile: {12 ds_read | 24 MFMA} x2, mid-barrier, {stage t+2 | 24 MFMA} x2,
// vmcnt(8) (t+1 landed, t+2 in flight - never drains), barrier.
__global__ __launch_bounds__(512, 2) void gemm_split256(const __bf16* __restrict__ Ah,
                                                        const __bf16* __restrict__ Al,
                                                        const __bf16* __restrict__ Bh,
                                                        const __bf16* __restrict__ Bl,
                                                        float* __restrict__ C,
                                                        int K, int ldc) {
    __shared__ __bf16 sAh[2][8192], sAl[2][8192], sBh[2][8192], sBl[2][8192];
    const int tid = threadIdx.x;
    const int lane = tid & 63;
    const int wid = tid >> 6;       // 0..7
    const int wrw = wid >> 2;       // 0..1  (M half)
    const int wcw = wid & 3;        // 0..3  (N quarter)
    const int bm = blockIdx.y, bn = blockIdx.x;

    // staging map: row = tid&255, kb = (tid>>8) + 2q ; LDS elem = q*4096 + tid*8
    const int srow = tid & 255;
    const int skb0 = tid >> 8;      // 0..1
    const size_t aGrow = (size_t)(bm * 256 + srow) * K;
    const size_t bGrow = (size_t)(bn * 256 + srow) * K;

    f32x4 acc[8][4];
#pragma unroll
    for (int m = 0; m < 8; ++m)
#pragma unroll
        for (int n = 0; n < 4; ++n) acc[m][n] = (f32x4){0.f, 0.f, 0.f, 0.f};

    const int kb = lane >> 4, rr = lane & 15;
    const int offA0 = kb * 2048 + (wrw * 128 + rr) * 8;  // + m*128
    const int offB0 = kb * 2048 + (wcw * 64 + rr) * 8;   // + n*128

    auto stage_half = [&](int b, int k0, int q) {
        const int lo = q * 4096 + tid * 8;
        const size_t go = (size_t)k0 + (size_t)((skb0 + 2 * q) * 8);
        gl_lds16(Ah + aGrow + go, &sAh[b][lo]);
        gl_lds16(Al + aGrow + go, &sAl[b][lo]);
        gl_lds16(Bh + bGrow + go, &sBh[b][lo]);
        gl_lds16(Bl + bGrow + go, &sBl[b][lo]);
    };

    const int nt = K >> 5;
    stage_half(0, 0, 0);  stage_half(0, 0, 1);
    stage_half(1, 32, 0); stage_half(1, 32, 1);
    asm volatile("s_waitcnt vmcnt(8)" ::: "memory");
    __builtin_amdgcn_s_barrier();

    for (int t = 0; t < nt; ++t) {
        const int cur = t & 1;
        const __bf16* pAh = sAh[cur];
        const __bf16* pAl = sAl[cur];
        const __bf16* pBh = sBh[cur];
        const __bf16* pBl = sBl[cur];

        bf16x8 fBh[4], fBl[4], fAh8[8], fAl8[8];
        // ---- P1: B(all) + A[0,1] reads, then MFMA m0,m1 ----
#pragma unroll
        for (int n = 0; n < 4; ++n) {
            fBh[n] = *(const bf16x8*)&pBh[offB0 + n * 128];
            fBl[n] = *(const bf16x8*)&pBl[offB0 + n * 128];
        }
#pragma unroll
        for (int m = 0; m < 2; ++m) {
            fAh8[m] = *(const bf16x8*)&pAh[offA0 + m * 128];
            fAl8[m] = *(const bf16x8*)&pAl[offA0 + m * 128];
        }
        asm volatile("s_waitcnt lgkmcnt(0)" ::: "memory");
        __builtin_amdgcn_sched_barrier(0);
        __builtin_amdgcn_s_setprio(1);
#pragma unroll
        for (int m = 0; m < 2; ++m)
#pragma unroll
            for (int n = 0; n < 4; ++n) {
                acc[m][n] = __builtin_amdgcn_mfma_f32_16x16x32_bf16(fAh8[m], fBh[n], acc[m][n], 0, 0, 0);
                acc[m][n] = __builtin_amdgcn_mfma_f32_16x16x32_bf16(fAh8[m], fBl[n], acc[m][n], 0, 0, 0);
                acc[m][n] = __builtin_amdgcn_mfma_f32_16x16x32_bf16(fAl8[m], fBh[n], acc[m][n], 0, 0, 0);
            }
        __builtin_amdgcn_s_setprio(0);
        // ---- P2: A[2..7] reads, then MFMA m2,m3 ----
#pragma unroll
        for (int m = 2; m < 8; ++m) {
            fAh8[m] = *(const bf16x8*)&pAh[offA0 + m * 128];
            fAl8[m] = *(const bf16x8*)&pAl[offA0 + m * 128];
        }
        asm volatile("s_waitcnt lgkmcnt(0)" ::: "memory");
        __builtin_amdgcn_sched_barrier(0);
        __builtin_amdgcn_s_setprio(1);
#pragma unroll
        for (int m = 2; m < 4; ++m)
#pragma unroll
            for (int n = 0; n < 4; ++n) {
                acc[m][n] = __builtin_amdgcn_mfma_f32_16x16x32_bf16(fAh8[m], fBh[n], acc[m][n], 0, 0, 0);
                acc[m][n] = __builtin_amdgcn_mfma_f32_16x16x32_bf16(fAh8[m], fBl[n], acc[m][n], 0, 0, 0);
                acc[m][n] = __builtin_amdgcn_mfma_f32_16x16x32_bf16(fAl8[m], fBh[n], acc[m][n], 0, 0, 0);
            }
        __builtin_amdgcn_s_setprio(0);
        // all waves done reading buf[cur] -> safe to refill
        __builtin_amdgcn_s_barrier();
        // ---- P3: stage t+2 (half) | MFMA m4,m5 ----
        if (t + 2 < nt) stage_half(cur, (t + 2) << 5, 0);
        __builtin_amdgcn_s_setprio(1);
#pragma unroll
        for (int m = 4; m < 6; ++m)
#pragma unroll
            for (int n = 0; n < 4; ++n) {
                acc[m][n] = __builtin_amdgcn_mfma_f32_16x16x32_bf16(fAh8[m], fBh[n], acc[m][n], 0, 0, 0);
                acc[m][n] = __builtin_amdgcn_mfma_f32_16x16x32_bf16(fAh8[m], fBl[n], acc[m][n], 0, 0, 0);
                acc[m][n] = __builtin_amdgcn_mfma_f32_16x16x32_bf16(fAl8[m], fBh[n], acc[m][n], 0, 0, 0);
            }
        __builtin_amdgcn_s_setprio(0);
        // ---- P4: stage t+2 (half) | MFMA m6,m7 ----
        if (t + 2 < nt) stage_half(cur, (t + 2) << 5, 1);
        __builtin_amdgcn_s_setprio(1);
#pragma unroll
        for (int m = 6; m < 8; ++m)
#pragma unroll
            for (int n = 0; n < 4; ++n) {
                acc[m][n] = __builtin_amdgcn_mfma_f32_16x16x32_bf16(fAh8[m], fBh[n], acc[m][n], 0, 0, 0);
                acc[m][n] = __builtin_amdgcn_mfma_f32_16x16x32_bf16(fAh8[m], fBl[n], acc[m][n], 0, 0, 0);
                acc[m][n] = __builtin_amdgcn_mfma_f32_16x16x32_bf16(fAl8[m], fBh[n], acc[m][n], 0, 0, 0);
            }
        __builtin_amdgcn_s_setprio(0);
        if (t + 2 < nt) asm volatile("s_waitcnt vmcnt(8)" ::: "memory");
        else            asm volatile("s_waitcnt vmcnt(0)" ::: "memory");
        __builtin_amdgcn_s_barrier();
    }

    const int rq = lane >> 4;
#pragma unroll
    for (int m = 0; m < 8; ++m)
#pragma unroll
        for (int n = 0; n < 4; ++n) {
            int col = bn * 256 + wcw * 64 + n * 16 + rr;
            int row0 = bm * 256 + wrw * 128 + m * 16 + rq * 4;
#pragma unroll
            for (int j = 0; j < 4; ++j)
                C[(size_t)(row0 + j) * ldc + col] = acc[m][n][j];
        }
}

// ============ 128x128 split-bf16 MFMA GEMM (for out_proj; depth-2 prefetch) ============
__global__ __launch_bounds__(256, 2) void gemm_split(const __bf16* __restrict__ Ah,
                                                     const __bf16* __restrict__ Al,
                                                     const __bf16* __restrict__ Bh,
                                                     const __bf16* __restrict__ Bl,
                                                     float* __restrict__ C,
                                                     int K, int ldc) {
    __shared__ __bf16 sAh[2][4096], sAl[2][4096], sBh[2][4096], sBl[2][4096];
    const int tid = threadIdx.x;
    const int lane = tid & 63;
    const int wid = tid >> 6;
    const int wrw = wid >> 1, wcw = wid & 1;
    const int bm = blockIdx.y, bn = blockIdx.x;

    const int r = tid & 127;
    const int kbq8 = (tid >> 7) * 8;
    const size_t arow = (size_t)(bm * 128 + r) * K;
    const size_t brow = (size_t)(bn * 128 + r) * K;

    f32x4 acc[4][4];
#pragma unroll
    for (int m = 0; m < 4; ++m)
#pragma unroll
        for (int n = 0; n < 4; ++n) acc[m][n] = (f32x4){0.f, 0.f, 0.f, 0.f};

    const int kb = lane >> 4, rr = lane & 15;

    auto stage = [&](int b, int k0) {
#pragma unroll
        for (int q = 0; q < 2; ++q) {
            const int lo = q * 2048 + tid * 8;
            const size_t go = (size_t)k0 + q * 16 + kbq8;
            gl_lds16(Ah + arow + go, &sAh[b][lo]);
            gl_lds16(Al + arow + go, &sAl[b][lo]);
            gl_lds16(Bh + brow + go, &sBh[b][lo]);
            gl_lds16(Bl + brow + go, &sBl[b][lo]);
        }
    };

    const int nt = K >> 5;
    stage(0, 0);
    stage(1, 32);
    asm volatile("s_waitcnt vmcnt(8)" ::: "memory");
    __builtin_amdgcn_s_barrier();

    for (int t = 0; t < nt; ++t) {
        const int cur = t & 1;
        bf16x8 fAh[4], fAl[4], fBh[4], fBl[4];
#pragma unroll
        for (int m = 0; m < 4; ++m) {
            int off = kb * 1024 + (wrw * 64 + m * 16 + rr) * 8;
            fAh[m] = *(const bf16x8*)&sAh[cur][off];
            fAl[m] = *(const bf16x8*)&sAl[cur][off];
        }
#pragma unroll
        for (int n = 0; n < 4; ++n) {
            int off = kb * 1024 + (wcw * 64 + n * 16 + rr) * 8;
            fBh[n] = *(const bf16x8*)&sBh[cur][off];
            fBl[n] = *(const bf16x8*)&sBl[cur][off];
        }
        asm volatile("s_waitcnt lgkmcnt(0)" ::: "memory");
        __builtin_amdgcn_sched_barrier(0);
        __builtin_amdgcn_s_barrier();
        __builtin_amdgcn_sched_barrier(0);
        if (t + 2 < nt) stage(cur, (t + 2) << 5);
        __builtin_amdgcn_s_setprio(1);
#pragma unroll
        for (int m = 0; m < 4; ++m)
#pragma unroll
            for (int n = 0; n < 4; ++n) {
                acc[m][n] = __builtin_amdgcn_mfma_f32_16x16x32_bf16(fAh[m], fBh[n], acc[m][n], 0, 0, 0);
                acc[m][n] = __builtin_amdgcn_mfma_f32_16x16x32_bf16(fAh[m], fBl[n], acc[m][n], 0, 0, 0);
                acc[m][n] = __builtin_amdgcn_mfma_f32_16x16x32_bf16(fAl[m], fBh[n], acc[m][n], 0, 0, 0);
            }
        __builtin_amdgcn_s_setprio(0);
        if (t + 2 < nt) asm volatile("s_waitcnt vmcnt(8)" ::: "memory");
        else            asm volatile("s_waitcnt vmcnt(0)" ::: "memory");
        __builtin_amdgcn_s_barrier();
    }

    const int rq = lane >> 4;
#pragma unroll
    for (int m = 0; m < 4; ++m)
#pragma unroll
        for (int n = 0; n < 4; ++n) {
            int col = bn * 128 + wcw * 64 + n * 16 + rr;
            int row0 = bm * 128 + wrw * 64 + m * 16 + rq * 4;
#pragma unroll
            for (int j = 0; j < 4; ++j)
                C[(size_t)(row0 + j) * ldc + col] = acc[m][n][j];
        }
}

// ============ scan phase 1: local chunk scans (fused conv+SiLU) ============
__global__ __launch_bounds__(256) void scan_phase1(const float* __restrict__ xz,
                                                   const float* __restrict__ coef,
                                                   const float* __restrict__ conv_w,
                                                   const float* __restrict__ conv_b,
                                                   float* __restrict__ states,
                                                   float* __restrict__ look) {
    int t = blockIdx.x * 256 + threadIdx.x;   // t = h*NC + c
    int c = t & (NC - 1);
    int h = t >> 5;

    const int HN = H_DIM * N_ST;
    float wr[N_ST], wi[N_ST];
#pragma unroll
    for (int n = 0; n < N_ST; ++n) {
        wr[n] = coef[h * N_ST + n];
        wi[n] = coef[HN + h * N_ST + n];
    }
    float cw0 = conv_w[h * 4 + 0], cw1 = conv_w[h * 4 + 1];
    float cw2 = conv_w[h * 4 + 2], cw3 = conv_w[h * 4 + 3];
    float cb = conv_b[h];

    const float* xrow = xz + (size_t)h * L_SEQ + c * CL;
    float x3 = 0.f, x2 = 0.f, x1 = 0.f;
    if (c > 0) {
        float4 p = *(const float4*)(xrow - 4);
        x3 = p.y; x2 = p.z; x1 = p.w;
    }
    *(float4*)(look + (size_t)t * 4) = make_float4(x3, x2, x1, 0.f);

    float sr[N_ST], si[N_ST];
#pragma unroll
    for (int n = 0; n < N_ST; ++n) { sr[n] = 0.f; si[n] = 0.f; }

    for (int j = 0; j < CL; j += 4) {
        float4 v = *(const float4*)(xrow + j);
        float xv[4] = {v.x, v.y, v.z, v.w};
#pragma unroll
        for (int k = 0; k < 4; ++k) {
            float u = cw0 * x3 + cw1 * x2 + cw2 * x1 + cw3 * xv[k] + cb;
            float xc = u / (1.f + __expf(-u));
            x3 = x2; x2 = x1; x1 = xv[k];
#pragma unroll
            for (int n = 0; n < N_ST; ++n) {
                float nr = wr[n] * sr[n] - wi[n] * si[n] + xc;
                float ni = wr[n] * si[n] + wi[n] * sr[n];
                sr[n] = nr; si[n] = ni;
            }
        }
    }
    float* st = states + (size_t)t * (N_ST * 2);
#pragma unroll
    for (int n = 0; n < N_ST; ++n) { st[2 * n] = sr[n]; st[2 * n + 1] = si[n]; }
}

// ============ scan phase 2: combine chunk states -> chunk init states ============
__global__ __launch_bounds__(256) void scan_phase2(const float* __restrict__ coef,
                                                   float* __restrict__ states) {
    int h = blockIdx.x * 256 + threadIdx.x;
    if (h >= H_DIM) return;
    const int HN = H_DIM * N_ST;
    float pr[N_ST], pi[N_ST];
#pragma unroll
    for (int n = 0; n < N_ST; ++n) {
        pr[n] = coef[4 * HN + h * N_ST + n];
        pi[n] = coef[5 * HN + h * N_ST + n];
    }
    float sr[N_ST], si[N_ST];
#pragma unroll
    for (int n = 0; n < N_ST; ++n) { sr[n] = 0.f; si[n] = 0.f; }
    float* base = states + (size_t)h * NC * (N_ST * 2);
    for (int c = 0; c < NC; ++c) {
        float* st = base + c * (N_ST * 2);
#pragma unroll
        for (int n = 0; n < N_ST; ++n) {
            float lr = st[2 * n], li = st[2 * n + 1];
            st[2 * n] = sr[n]; st[2 * n + 1] = si[n];
            float nr = pr[n] * sr[n] - pi[n] * si[n] + lr;
            float ni = pr[n] * si[n] + pi[n] * sr[n] + li;
            sr[n] = nr; si[n] = ni;
        }
    }
}

// ============ scan phase 3: replay, fused D-skip + gate; writes y f32 OVER x ============
__global__ __launch_bounds__(256) void scan_phase3(float* __restrict__ xz,
                                                   const float* __restrict__ coef,
                                                   const float* __restrict__ conv_w,
                                                   const float* __restrict__ conv_b,
                                                   const float* __restrict__ Dvec,
                                                   const float* __restrict__ states,
                                                   const float* __restrict__ look) {
    int t = blockIdx.x * 256 + threadIdx.x;
    int c = t & (NC - 1);
    int h = t >> 5;

    const int HN = H_DIM * N_ST;
    float wr[N_ST], wi[N_ST], Ctr[N_ST], Cti[N_ST];
#pragma unroll
    for (int n = 0; n < N_ST; ++n) {
        wr[n]  = coef[h * N_ST + n];
        wi[n]  = coef[HN + h * N_ST + n];
        Ctr[n] = coef[2 * HN + h * N_ST + n];
        Cti[n] = coef[3 * HN + h * N_ST + n];
    }
    float cw0 = conv_w[h * 4 + 0], cw1 = conv_w[h * 4 + 1];
    float cw2 = conv_w[h * 4 + 2], cw3 = conv_w[h * 4 + 3];
    float cb = conv_b[h];
    float Dh = Dvec[h];

    float* xrow = xz + (size_t)h * L_SEQ + c * CL;
    const float* zrow = xz + (size_t)(H_DIM + h) * L_SEQ + c * CL;

    float4 lk = *(const float4*)(look + (size_t)t * 4);
    float x3 = lk.x, x2 = lk.y, x1 = lk.z;

    const float* st = states + (size_t)t * (N_ST * 2);
    float sr[N_ST], si[N_ST];
#pragma unroll
    for (int n = 0; n < N_ST; ++n) { sr[n] = st[2 * n]; si[n] = st[2 * n + 1]; }

    for (int j = 0; j < CL; j += 4) {
        float4 v = *(const float4*)(xrow + j);
        float4 zv = *(const float4*)(zrow + j);
        float xv[4] = {v.x, v.y, v.z, v.w};
        float zz[4] = {zv.x, zv.y, zv.z, zv.w};
        float out[4];
#pragma unroll
        for (int k = 0; k < 4; ++k) {
            float u = cw0 * x3 + cw1 * x2 + cw2 * x1 + cw3 * xv[k] + cb;
            float xc = u / (1.f + __expf(-u));
            x3 = x2; x2 = x1; x1 = xv[k];
            float accy = 0.f;
#pragma unroll
            for (int n = 0; n < N_ST; ++n) {
                float nr = wr[n] * sr[n] - wi[n] * si[n] + xc;
                float ni = wr[n] * si[n] + wi[n] * sr[n];
                sr[n] = nr; si[n] = ni;
                accy += Ctr[n] * nr - Cti[n] * ni;
            }
            float yv = 2.f * accy + Dh * xc;
            float g = zz[k] / (1.f + __expf(-zz[k]));
            out[k] = yv * g;
        }
        *(float4*)(xrow + j) = make_float4(out[0], out[1], out[2], out[3]);
    }
}

// ============ transpose + split: y f32 [H][L] -> yTh/yTl bf16 [L][H] ============
__global__ __launch_bounds__(256) void transpose_split(const float* __restrict__ y,
                                                       __bf16* __restrict__ th,
                                                       __bf16* __restrict__ tl) {
    __shared__ float tile[64][65];
    const int l0 = blockIdx.x * 64, h0 = blockIdx.y * 64;
    const int tid = threadIdx.x;
    const int r = tid >> 4, c4 = (tid & 15) * 4;
#pragma unroll
    for (int p = 0; p < 4; ++p) {
        float4 v = *(const float4*)(y + (size_t)(h0 + r + p * 16) * L_SEQ + l0 + c4);
        tile[r + p * 16][c4 + 0] = v.x;
        tile[r + p * 16][c4 + 1] = v.y;
        tile[r + p * 16][c4 + 2] = v.z;
        tile[r + p * 16][c4 + 3] = v.w;
    }
    __syncthreads();
    const int l = tid >> 2, hb = (tid & 3) * 16;
    float vals[16];
#pragma unroll
    for (int j = 0; j < 16; ++j) vals[j] = tile[hb + j][l];
    bf16x8 hv0, hv1, lv0, lv1;
#pragma unroll
    for (int j = 0; j < 8; ++j) {
        __bf16 hbv = (__bf16)vals[j];
        hv0[j] = hbv;
        lv0[j] = (__bf16)(vals[j] - (float)hbv);
        __bf16 hbv2 = (__bf16)vals[j + 8];
        hv1[j] = hbv2;
        lv1[j] = (__bf16)(vals[j + 8] - (float)hbv2);
    }
    size_t base = (size_t)(l0 + l) * H_DIM + h0 + hb;
    *(bf16x8*)&th[base] = hv0;
    *(bf16x8*)&th[base + 8] = hv1;
    *(bf16x8*)&tl[base] = lv0;
    *(bf16x8*)&tl[base + 8] = lv1;
}

extern "C" void kernel_launch(void* const* d_in, const int* in_sizes, int n_in,
                              void* d_out, int out_size, void* d_ws, size_t ws_size,
                              hipStream_t stream) {
    const float* hid        = (const float*)d_in[0];
    const float* W_in       = (const float*)d_in[1];
    const float* conv_w     = (const float*)d_in[2];
    const float* conv_b     = (const float*)d_in[3];
    const float* log_dt     = (const float*)d_in[4];
    const float* log_A_real = (const float*)d_in[5];
    const float* A_imag     = (const float*)d_in[6];
    const float* C_re       = (const float*)d_in[7];
    const float* C_im       = (const float*)d_in[8];
    const float* Dv         = (const float*)d_in[9];
    const float* W_out      = (const float*)d_in[10];
    float* out = (float*)d_out;
    float* ws  = (float*)d_ws;

    float* xz      = ws + WS_XZ;
    __bf16* yTh    = (__bf16*)(ws + WS_YTH);
    __bf16* yTl    = (__bf16*)(ws + WS_YTL);
    float* coef    = ws + WS_COEF;
    float* states  = ws + WS_STATES;
    float* look    = ws + WS_LOOK;
    __bf16* Hh     = (__bf16*)(ws + WS_HH);
    __bf16* Hl     = (__bf16*)(ws + WS_HL);
    __bf16* Wih    = (__bf16*)(ws + WS_WIH);
    __bf16* Wil    = (__bf16*)(ws + WS_WIL);
    __bf16* Woh    = (__bf16*)(ws + WS_WOH);
    __bf16* Wol    = (__bf16*)(ws + WS_WOL);

    coef_kernel<<<(H_DIM * N_ST + 255) / 256, 256, 0, stream>>>(
        log_dt, log_A_real, A_imag, C_re, C_im, coef);

    cvt_split4<<<(2 * H_DIM * DMODEL / 4 + 255) / 256, 256, 0, stream>>>(W_in, Wih, Wil, 2 * H_DIM * DMODEL / 4);
    cvt_split4<<<(DMODEL * H_DIM / 4 + 255) / 256, 256, 0, stream>>>(W_out, Woh, Wol, DMODEL * H_DIM / 4);

    const int nscan = H_DIM * NC;              // 65536
    dim3 gIn2(L_SEQ / 256, 2 * H_DIM / 256);   // (16,16) -> 256 blocks, 1/CU
    dim3 gOut(DMODEL / 128, L_SEQ / 128);      // (8,32)
    dim3 gTr(L_SEQ / 64, H_DIM / 64);          // (64,32)

    for (int b = 0; b < B_SZ; ++b) {
        const float* hid_b = hid + (size_t)b * L_SEQ * DMODEL;
        float* out_b = out + (size_t)b * L_SEQ * DMODEL;

        cvt_split4<<<(L_SEQ * DMODEL / 4 + 255) / 256, 256, 0, stream>>>(hid_b, Hh, Hl, L_SEQ * DMODEL / 4);
        gemm_split256<<<gIn2, 512, 0, stream>>>(Wih, Wil, Hh, Hl, xz, DMODEL, L_SEQ);
        scan_phase1<<<nscan / 256, 256, 0, stream>>>(xz, coef, conv_w, conv_b, states, look);
        scan_phase2<<<(H_DIM + 255) / 256, 256, 0, stream>>>(coef, states);
        scan_phase3<<<nscan / 256, 256, 0, stream>>>(xz, coef, conv_w, conv_b, Dv, states, look);
        transpose_split<<<gTr, 256, 0, stream>>>(xz, yTh, yTl);
        gemm_split<<<gOut, 256, 0, stream>>>(yTh, yTl, Woh, Wol, out_b, H_DIM, DMODEL);
    }
}